// Round 9
// baseline (1082.723 us; speedup 1.0000x reference)
//
#include <hip/hip_runtime.h>
#include <math.h>

#define K_IN 12288
#define HID  1024
#define G4   4096
#define TS   256
#define NKS  8
#define KSP  (K_IN / NKS)   // 1536
#define NST  (KSP / 16)     // 96 k-steps (even -> 2x unrolled pipeline)

typedef unsigned long long u64;
typedef unsigned int u32;
typedef __attribute__((ext_vector_type(4))) float f32x4;
typedef __attribute__((ext_vector_type(16))) float f32x16;
typedef __attribute__((ext_vector_type(8))) _Float16 half8;
typedef __attribute__((ext_vector_type(4))) _Float16 half4;

// ---------------------------------------------------------------------------
// Kernel 1: partial GEMM via f16-split MFMA, LDS-staged once-per-element
// conversion, 2-deep register prefetch, atomic-add accumulation.
//   xprojT[j][t] += dot(X[t,kslice], W[j,kslice])   (j-major)
//
// vs r8 (measured ~360 us):
//  - grid FIXED at (32 j-tiles, 8 k-splits) = 256 blocks — parallelism no
//    longer gated on ws_size (r8's nks was ws-dependent; if ws<13MB it ran
//    32 blocks x 768 latency-stalled steps ~ 330 us — the prime suspect).
//    Partials atomicAdd into xprojT (memset-zeroed; biases folded into lstm).
//  - 2-deep prefetch: two named register sets (A/B), 2x-unrolled loop; load
//    for step s+2 issues during step s -> ~2 steps (~1000cy) of MFMA+ds work
//    cover the ~900cy HBM latency that r8's 1-deep scheme exposed every step.
// f16 split a = hi+lo, product hh+hl+lh via mfma_f32_32x32x16_f16 (numerics
// HW-validated r5/r8, absmax unchanged vs fp32).
// C/D mapping (HW-validated): col=lane&31=t, row=(rg&3)+8*(rg>>2)+4*kh=j.
// ---------------------------------------------------------------------------
__global__ __launch_bounds__(512, 2) void xproj_gemm(
    const float* __restrict__ X,     // (256, 12288)
    const float* __restrict__ W,     // (4096, 12288)
    float* __restrict__ xprojT)      // (4096, 256)  j-major, pre-zeroed
{
  __shared__ __align__(16) _Float16 Ahi[2][128][8];  // [kh][j-local][8 f16]
  __shared__ __align__(16) _Float16 Alo[2][128][8];
  __shared__ __align__(16) _Float16 Bhi[2][256][8];  // [kh][t][8 f16]
  __shared__ __align__(16) _Float16 Blo[2][256][8];

  const int tid = threadIdx.x;
  const int wave = tid >> 6;          // 0..7
  const int lane = tid & 63;
  const int l31 = lane & 31;
  const int kh = lane >> 5;           // 0/1: k-half of the fragment

  const int j0 = blockIdx.x * 128;
  const int kbeg = blockIdx.y * KSP;

  const int jw = (wave & 1) * 64;     // wave j-sub (0/64)
  const int tw = (wave >> 1) * 64;    // wave t-sub (0/64/128/192)

  // staging mapping (coalesced: 4 lanes cover one 64B row-chunk)
  const int wrow = tid >> 2;          // 0..127
  const int wkq  = tid & 3;           // float4 within 16 k
  const int xrow = tid >> 1;          // 0..255
  const int xkq  = tid & 1;           // 8-float half within 16 k

  const float* wsrc = W + (size_t)(j0 + wrow) * K_IN + kbeg + wkq * 4;
  const float* xsrc = X + (size_t)xrow * K_IN + kbeg + xkq * 8;

  f32x16 acc[2][2];
#pragma unroll
  for (int mi = 0; mi < 2; ++mi)
#pragma unroll
    for (int ni = 0; ni < 2; ++ni)
#pragma unroll
      for (int e = 0; e < 16; ++e) acc[mi][ni][e] = 0.f;

  // 2-deep prologue: set A = k-step 0, set B = k-step 1
  f32x4 wvA  = *(const f32x4*)(wsrc);
  f32x4 xv0A = *(const f32x4*)(xsrc);
  f32x4 xv1A = *(const f32x4*)(xsrc + 4);
  f32x4 wvB  = *(const f32x4*)(wsrc + 16);
  f32x4 xv0B = *(const f32x4*)(xsrc + 16);
  f32x4 xv1B = *(const f32x4*)(xsrc + 16 + 4);

#define STAGE(WV, XV0, XV1)                                                  \
  {                                                                          \
    half4 hw, lw;                                                            \
    _Pragma("unroll")                                                        \
    for (int e = 0; e < 4; ++e) {                                            \
      _Float16 h = (_Float16)WV[e];                                          \
      hw[e] = h;                                                             \
      lw[e] = (_Float16)(WV[e] - (float)h);                                  \
    }                                                                        \
    *(half4*)&Ahi[wkq >> 1][wrow][(wkq & 1) * 4] = hw;                       \
    *(half4*)&Alo[wkq >> 1][wrow][(wkq & 1) * 4] = lw;                       \
    half8 hx, lx;                                                            \
    _Pragma("unroll")                                                        \
    for (int e = 0; e < 4; ++e) {                                            \
      _Float16 h0 = (_Float16)XV0[e];                                        \
      hx[e] = h0;                                                            \
      lx[e] = (_Float16)(XV0[e] - (float)h0);                                \
      _Float16 h1 = (_Float16)XV1[e];                                        \
      hx[e + 4] = h1;                                                        \
      lx[e + 4] = (_Float16)(XV1[e] - (float)h1);                            \
    }                                                                        \
    *(half8*)&Bhi[xkq][xrow][0] = hx;                                        \
    *(half8*)&Blo[xkq][xrow][0] = lx;                                        \
  }

#define COMPUTE()                                                            \
  {                                                                          \
    half8 aH[2], aL[2], bH[2], bL[2];                                        \
    _Pragma("unroll")                                                        \
    for (int mi = 0; mi < 2; ++mi) {                                         \
      aH[mi] = *(const half8*)&Ahi[kh][jw + mi * 32 + l31][0];               \
      aL[mi] = *(const half8*)&Alo[kh][jw + mi * 32 + l31][0];               \
    }                                                                        \
    _Pragma("unroll")                                                        \
    for (int ni = 0; ni < 2; ++ni) {                                         \
      bH[ni] = *(const half8*)&Bhi[kh][tw + ni * 32 + l31][0];               \
      bL[ni] = *(const half8*)&Blo[kh][tw + ni * 32 + l31][0];               \
    }                                                                        \
    acc[0][0] = __builtin_amdgcn_mfma_f32_32x32x16_f16(aH[0], bH[0], acc[0][0], 0, 0, 0); \
    acc[0][1] = __builtin_amdgcn_mfma_f32_32x32x16_f16(aH[0], bH[1], acc[0][1], 0, 0, 0); \
    acc[1][0] = __builtin_amdgcn_mfma_f32_32x32x16_f16(aH[1], bH[0], acc[1][0], 0, 0, 0); \
    acc[1][1] = __builtin_amdgcn_mfma_f32_32x32x16_f16(aH[1], bH[1], acc[1][1], 0, 0, 0); \
    acc[0][0] = __builtin_amdgcn_mfma_f32_32x32x16_f16(aH[0], bL[0], acc[0][0], 0, 0, 0); \
    acc[0][1] = __builtin_amdgcn_mfma_f32_32x32x16_f16(aH[0], bL[1], acc[0][1], 0, 0, 0); \
    acc[1][0] = __builtin_amdgcn_mfma_f32_32x32x16_f16(aH[1], bL[0], acc[1][0], 0, 0, 0); \
    acc[1][1] = __builtin_amdgcn_mfma_f32_32x32x16_f16(aH[1], bL[1], acc[1][1], 0, 0, 0); \
    acc[0][0] = __builtin_amdgcn_mfma_f32_32x32x16_f16(aL[0], bH[0], acc[0][0], 0, 0, 0); \
    acc[0][1] = __builtin_amdgcn_mfma_f32_32x32x16_f16(aL[0], bH[1], acc[0][1], 0, 0, 0); \
    acc[1][0] = __builtin_amdgcn_mfma_f32_32x32x16_f16(aL[1], bH[0], acc[1][0], 0, 0, 0); \
    acc[1][1] = __builtin_amdgcn_mfma_f32_32x32x16_f16(aL[1], bH[1], acc[1][1], 0, 0, 0); \
  }

  for (int s = 0; s < NST; s += 2) {
    // even substep: stage set A (k-step s), prefetch A <- k-step s+2
    STAGE(wvA, xv0A, xv1A);
    __syncthreads();
    if (s + 2 < NST) {
      const int ko = (s + 2) * 16;
      wvA  = *(const f32x4*)(wsrc + ko);
      xv0A = *(const f32x4*)(xsrc + ko);
      xv1A = *(const f32x4*)(xsrc + ko + 4);
    }
    COMPUTE();
    __syncthreads();
    // odd substep: stage set B (k-step s+1), prefetch B <- k-step s+3
    STAGE(wvB, xv0B, xv1B);
    __syncthreads();
    if (s + 3 < NST) {
      const int ko = (s + 3) * 16;
      wvB  = *(const f32x4*)(wsrc + ko);
      xv0B = *(const f32x4*)(xsrc + ko);
      xv1B = *(const f32x4*)(xsrc + ko + 4);
    }
    COMPUTE();
    __syncthreads();
  }

  // epilogue: accumulate partial into xprojT (device-scope fp32 atomics;
  // 8 k-split blocks per (j,t) — order-independent up to fp32 rounding)
#pragma unroll
  for (int mi = 0; mi < 2; ++mi)
#pragma unroll
    for (int ni = 0; ni < 2; ++ni)
#pragma unroll
      for (int rg = 0; rg < 16; ++rg) {
        const int j = j0 + jw + mi * 32 + (rg & 3) + 8 * (rg >> 2) + 4 * kh;
        const int t = tw + ni * 32 + l31;
        atomicAdd(&xprojT[(size_t)j * TS + t], acc[mi][ni][rg]);
      }
}

// ---------------------------------------------------------------------------
// Kernel 2: persistent LSTM scan — r4/r8 proven structure (638 us), with two
// strictly-local changes:
//  (a) 4-way split accumulator in the h*W dot (128-FMA dep chain 512cy ->
//      ~160cy; this exact arithmetic passed in r5),
//  (b) biases folded in (xproj is now raw GEMM output): gsum += bias.
// Protocol (spin slot 0 + batch verify, B1/B2/B3, gates_lds, c_lds,
// single-wave tid<8 publish) byte-identical to the proven kernel.
// ---------------------------------------------------------------------------
#define NWG 128
#define UPW 8

__global__ __launch_bounds__(256, 1) void lstm_scan(
    const float* __restrict__ W_hh,    // (4096, 1024)
    const float* __restrict__ xprojT,  // (4096, 256)  j-major, no bias
    const float* __restrict__ b_ih, const float* __restrict__ b_hh,
    u64* __restrict__ hmsg)            // (2, 1024) packed {tag,val}
{
  const int tid = threadIdx.x;
  const int w = blockIdx.x;
  const int u0 = w * UPW;
  const int r = tid >> 3;            // 0..31 local row
  const int sub = tid & 7;           // 8 lanes per row, 128 elems each
  const int gate = r >> 3;           // 0..3
  const int uu = r & 7;              // 0..7
  const int hrow = gate * HID + u0 + uu;

  __shared__ __align__(16) float h_lds[8 * 132];
  __shared__ float gates_lds[32];
  __shared__ float c_lds[UPW];

  // my 128-float W_hh segment in registers
  float4 Wreg[32];
  const float4* wp = (const float4*)(W_hh + (size_t)hrow * HID + sub * 128);
#pragma unroll
  for (int i = 0; i < 32; ++i) Wreg[i] = wp[i];

  const float* xrow = xprojT + (size_t)hrow * TS;
  const float bias = b_ih[hrow] + b_hh[hrow];

  if (tid < UPW) c_lds[tid] = 0.f;
  __syncthreads();

  for (int t = 0; t < TS; ++t) {
    // prefetch my xproj element early (hides L1/L2 latency behind the spin)
    float xp = 0.f;
    if (sub == 0) xp = xrow[t] + bias;

    float p0 = 0.f, p1 = 0.f, p2 = 0.f, p3 = 0.f;
    if (t > 0) {
      const u64* slot = hmsg + (t & 1) * HID;
      const u32 tt = (u32)t;
      u64 m0, m1, m2, m3;
      // spin on slot 0 only (1 load/thread/iter — proven-safe poll rate)
      do {
        m0 = __hip_atomic_load(&slot[tid * 4 + 0], __ATOMIC_RELAXED,
                               __HIP_MEMORY_SCOPE_AGENT);
      } while ((u32)(m0 >> 32) != tt);
      // slots 1-3: batch issue (one round-trip), then verify
      m1 = __hip_atomic_load(&slot[tid * 4 + 1], __ATOMIC_RELAXED,
                             __HIP_MEMORY_SCOPE_AGENT);
      m2 = __hip_atomic_load(&slot[tid * 4 + 2], __ATOMIC_RELAXED,
                             __HIP_MEMORY_SCOPE_AGENT);
      m3 = __hip_atomic_load(&slot[tid * 4 + 3], __ATOMIC_RELAXED,
                             __HIP_MEMORY_SCOPE_AGENT);
      while ((u32)(m1 >> 32) != tt)
        m1 = __hip_atomic_load(&slot[tid * 4 + 1], __ATOMIC_RELAXED,
                               __HIP_MEMORY_SCOPE_AGENT);
      while ((u32)(m2 >> 32) != tt)
        m2 = __hip_atomic_load(&slot[tid * 4 + 2], __ATOMIC_RELAXED,
                               __HIP_MEMORY_SCOPE_AGENT);
      while ((u32)(m3 >> 32) != tt)
        m3 = __hip_atomic_load(&slot[tid * 4 + 3], __ATOMIC_RELAXED,
                               __HIP_MEMORY_SCOPE_AGENT);
      __syncthreads();  // B1: prev step's h_lds readers done
      const int st = tid >> 5;
      const int off = (tid & 31) * 4;
      h_lds[st * 132 + off + 0] = __uint_as_float((u32)m0);
      h_lds[st * 132 + off + 1] = __uint_as_float((u32)m1);
      h_lds[st * 132 + off + 2] = __uint_as_float((u32)m2);
      h_lds[st * 132 + off + 3] = __uint_as_float((u32)m3);
      __syncthreads();  // B2: h_lds ready
      const float4* hl = (const float4*)(h_lds + sub * 132);
#pragma unroll
      for (int i = 0; i < 32; i += 4) {
        float4 h4;
        h4 = hl[i + 0];
        p0 += Wreg[i + 0].x * h4.x + Wreg[i + 0].y * h4.y +
              Wreg[i + 0].z * h4.z + Wreg[i + 0].w * h4.w;
        h4 = hl[i + 1];
        p1 += Wreg[i + 1].x * h4.x + Wreg[i + 1].y * h4.y +
              Wreg[i + 1].z * h4.z + Wreg[i + 1].w * h4.w;
        h4 = hl[i + 2];
        p2 += Wreg[i + 2].x * h4.x + Wreg[i + 2].y * h4.y +
              Wreg[i + 2].z * h4.z + Wreg[i + 2].w * h4.w;
        h4 = hl[i + 3];
        p3 += Wreg[i + 3].x * h4.x + Wreg[i + 3].y * h4.y +
              Wreg[i + 3].z * h4.z + Wreg[i + 3].w * h4.w;
      }
    }
    float partial = (p0 + p1) + (p2 + p3);
    // reduce across the 8 sub-lanes of this row (same wave)
    partial += __shfl_xor(partial, 1, 64);
    partial += __shfl_xor(partial, 2, 64);
    partial += __shfl_xor(partial, 4, 64);
    if (sub == 0) {
      float gsum = partial + xp;
      float act = (gate == 2) ? tanhf(gsum) : 1.f / (1.f + expf(-gsum));
      gates_lds[gate * 8 + uu] = act;
    }
    __syncthreads();  // B3: gates ready
    if (tid < UPW) {
      float iv = gates_lds[0 * 8 + tid];
      float fv = gates_lds[1 * 8 + tid];
      float gv = gates_lds[2 * 8 + tid];
      float ov = gates_lds[3 * 8 + tid];
      float c = fv * c_lds[tid] + iv * gv;
      c_lds[tid] = c;
      float hnew = ov * tanhf(c);
      u64 msg = ((u64)(u32)(t + 1) << 32) | (u64)__float_as_uint(hnew);
      __hip_atomic_store(&hmsg[((t + 1) & 1) * HID + u0 + tid], msg,
                         __ATOMIC_RELAXED, __HIP_MEMORY_SCOPE_AGENT);
    }
    // no trailing barrier needed: B1/B3 of the next iteration protect LDS
  }
}

// ---------------------------------------------------------------------------
// Kernel 3: out[j] = dot(fc_w[j,:], h_T) + fc_b[j].
// ---------------------------------------------------------------------------
__global__ __launch_bounds__(256) void fc_kernel(
    const float* __restrict__ fc_w,  // (12288, 1024)
    const float* __restrict__ fc_b,  // (12288)
    const u64* __restrict__ hmsg,    // h_T packed at slot 0
    float* __restrict__ out)         // (12288)
{
  __shared__ float h_s[HID];
  const int tid = threadIdx.x;
  for (int k = tid; k < HID; k += 256)
    h_s[k] = __uint_as_float((u32)hmsg[k]);
  __syncthreads();
  const int r = tid >> 2;    // 0..63
  const int sub = tid & 3;   // 256 elems each
  const int j = blockIdx.x * 64 + r;
  const float4* wrow = (const float4*)(fc_w + (size_t)j * HID + sub * 256);
  const float4* hp = (const float4*)(h_s + sub * 256);
  float s = 0.f;
#pragma unroll
  for (int i = 0; i < 64; ++i) {
    float4 wv = wrow[i];
    float4 hv = hp[i];
    s += wv.x * hv.x + wv.y * hv.y + wv.z * hv.z + wv.w * hv.w;
  }
  s += __shfl_xor(s, 1, 64);
  s += __shfl_xor(s, 2, 64);
  if (sub == 0) out[j] = s + fc_b[j];
}

// ---------------------------------------------------------------------------
extern "C" void kernel_launch(void* const* d_in, const int* in_sizes, int n_in,
                              void* d_out, int out_size, void* d_ws, size_t ws_size,
                              hipStream_t stream) {
  const float* frames = (const float*)d_in[0];  // (256,3,64,64)
  const float* W_ih   = (const float*)d_in[1];  // (4096,12288)
  const float* W_hh   = (const float*)d_in[2];  // (4096,1024)
  const float* b_ih   = (const float*)d_in[3];  // (4096)
  const float* b_hh   = (const float*)d_in[4];  // (4096)
  const float* fc_w   = (const float*)d_in[5];  // (12288,1024)
  const float* fc_b   = (const float*)d_in[6];  // (12288)
  float* out = (float*)d_out;

  const size_t XPROJ_BYTES = (size_t)TS * G4 * 4;  // 4 MB
  char* ws = (char*)d_ws;
  float* xprojT = (float*)ws;                        // 4 MB (j-major)
  u64*   hmsg   = (u64*)(ws + XPROJ_BYTES);          // 16 KB
  // hmsg deliberately NOT initialized: 0xAA poison tag never matches [1,256].

  // zero the atomic-accumulation target (stream-ordered before the GEMM)
  hipMemsetAsync(xprojT, 0, XPROJ_BYTES, stream);
  xproj_gemm<<<dim3(G4 / 128, NKS), 512, 0, stream>>>(frames, W_ih, xprojT);
  lstm_scan<<<dim3(NWG), 256, 0, stream>>>(W_hh, xprojT, b_ih, b_hh, hmsg);
  fc_kernel<<<dim3(12288 / 64), 256, 0, stream>>>(fc_w, fc_b, hmsg, out);
}

// Round 10
// 1035.424 us; speedup vs baseline: 1.0457x; 1.0457x over previous
//
#include <hip/hip_runtime.h>
#include <math.h>

#define K_IN 12288
#define HID  1024
#define G4   4096
#define TS   256
#define NKS  8
#define KSP  (K_IN / NKS)   // 1536
#define NST  (KSP / 16)     // 96 k-steps (even)

typedef unsigned long long u64;
typedef unsigned int u32;
typedef __attribute__((ext_vector_type(4))) float f32x4;
typedef __attribute__((ext_vector_type(16))) float f32x16;
typedef __attribute__((ext_vector_type(8))) _Float16 half8;
typedef __attribute__((ext_vector_type(4))) _Float16 half4;

// ---------------------------------------------------------------------------
// Kernel 1: partial GEMM via f16-split MFMA.
//   partial[j][t] = dot(X[t,kslice], W[j,kslice])   (j-major output)
// r9 post-mortem: the STAGE->barrier->COMPUTE->barrier schedule serialized
// 24KB of ds_writes against 64KB of ds_reads through the CU's LDS unit every
// k-step, with 2-way+ bank conflicts on the staging writes. Fixes:
//  - LDS double-buffer, ONE barrier per k-step: {STAGE(buf^1) || COMPUTE(buf)}
//    -> barrier. Writes drain under MFMA. (Hazards: STAGE(s+1) writes the
//    buffer last read by COMPUTE(s-1), which precedes barrier(s) in every
//    wave's program order; COMPUTE(s) reads the buffer staged before
//    barrier(s). One barrier suffices.)
//  - XOR bank swizzle (byte ^= kh*64) on BOTH ds_write and ds_read addresses:
//    every 8-lane pass of each LDS op hits 8 distinct 16B bank-groups
//    (verified lane-by-lane for A-write b64, B-write b128, frag reads b128).
//  - 2-deep register prefetch kept (A=even k-steps, B=odd; ~1600cy coverage).
// f16 split a=hi+lo, product hh+hl+lh (numerics HW-validated r5/r8/r9).
// C/D mapping (HW-validated): col=lane&31=t, row=(rg&3)+8*(rg>>2)+4*kh=j.
// ---------------------------------------------------------------------------
__global__ __launch_bounds__(512, 2) void xproj_gemm(
    const float* __restrict__ X,     // (256, 12288)
    const float* __restrict__ W,     // (4096, 12288)
    float* __restrict__ outp,        // xpartT (nks,4096,256) or xprojT
    int atomic_mode)
{
  // [dbuf][kh][row][8 f16]; swizzle applied on addresses below
  __shared__ __align__(16) _Float16 Ah[2][2][128][8];
  __shared__ __align__(16) _Float16 Al[2][2][128][8];
  __shared__ __align__(16) _Float16 Bh[2][2][256][8];
  __shared__ __align__(16) _Float16 Bl[2][2][256][8];

  const int tid = threadIdx.x;
  const int wave = tid >> 6;
  const int lane = tid & 63;
  const int l31 = lane & 31;
  const int kh = lane >> 5;

  const int j0 = blockIdx.x * 128;
  const int kbeg = blockIdx.y * KSP;

  const int jw = (wave & 1) * 64;
  const int tw = (wave >> 1) * 64;

  const int wrow = tid >> 2;          // 0..127
  const int wkq  = tid & 3;
  const int xrow = tid >> 1;          // 0..255
  const int xkq  = tid & 1;

  const float* wsrc = W + (size_t)(j0 + wrow) * K_IN + kbeg + wkq * 4;
  const float* xsrc = X + (size_t)xrow * K_IN + kbeg + xkq * 8;

  // swizzled LDS offsets (f16 units). write side:
  const int khw = wkq >> 1;
  const int a_woff = khw * 1024 + ((wrow * 8) ^ (khw * 32)) + (wkq & 1) * 4;
  const int b_woff = xkq * 2048 + ((xrow * 8) ^ (xkq * 32));
  // read side (per mi/ni, hoisted):
  int a_roff[2], b_roff[2];
#pragma unroll
  for (int mi = 0; mi < 2; ++mi)
    a_roff[mi] = kh * 1024 + (((jw + mi * 32 + l31) * 8) ^ (kh * 32));
#pragma unroll
  for (int ni = 0; ni < 2; ++ni)
    b_roff[ni] = kh * 2048 + (((tw + ni * 32 + l31) * 8) ^ (kh * 32));

  f32x16 acc[2][2];
#pragma unroll
  for (int mi = 0; mi < 2; ++mi)
#pragma unroll
    for (int ni = 0; ni < 2; ++ni)
#pragma unroll
      for (int e = 0; e < 16; ++e) acc[mi][ni][e] = 0.f;

#define STAGE(BUF, WV, XV0, XV1)                                             \
  {                                                                          \
    half4 hw, lw;                                                            \
    _Pragma("unroll")                                                        \
    for (int e = 0; e < 4; ++e) {                                            \
      _Float16 h = (_Float16)WV[e];                                          \
      hw[e] = h;                                                             \
      lw[e] = (_Float16)(WV[e] - (float)h);                                  \
    }                                                                        \
    *(half4*)(&Ah[BUF][0][0][0] + a_woff) = hw;                              \
    *(half4*)(&Al[BUF][0][0][0] + a_woff) = lw;                              \
    half8 hx, lx;                                                            \
    _Pragma("unroll")                                                        \
    for (int e = 0; e < 4; ++e) {                                            \
      _Float16 h0 = (_Float16)XV0[e];                                        \
      hx[e] = h0;                                                            \
      lx[e] = (_Float16)(XV0[e] - (float)h0);                                \
      _Float16 h1 = (_Float16)XV1[e];                                        \
      hx[e + 4] = h1;                                                        \
      lx[e + 4] = (_Float16)(XV1[e] - (float)h1);                            \
    }                                                                        \
    *(half8*)(&Bh[BUF][0][0][0] + b_woff) = hx;                              \
    *(half8*)(&Bl[BUF][0][0][0] + b_woff) = lx;                              \
  }

#define COMPUTE(BUF)                                                         \
  {                                                                          \
    half8 aH[2], aL[2], bH[2], bL[2];                                        \
    _Pragma("unroll")                                                        \
    for (int mi = 0; mi < 2; ++mi) {                                         \
      aH[mi] = *(const half8*)(&Ah[BUF][0][0][0] + a_roff[mi]);              \
      aL[mi] = *(const half8*)(&Al[BUF][0][0][0] + a_roff[mi]);              \
    }                                                                        \
    _Pragma("unroll")                                                        \
    for (int ni = 0; ni < 2; ++ni) {                                         \
      bH[ni] = *(const half8*)(&Bh[BUF][0][0][0] + b_roff[ni]);              \
      bL[ni] = *(const half8*)(&Bl[BUF][0][0][0] + b_roff[ni]);              \
    }                                                                        \
    acc[0][0] = __builtin_amdgcn_mfma_f32_32x32x16_f16(aH[0], bH[0], acc[0][0], 0, 0, 0); \
    acc[0][1] = __builtin_amdgcn_mfma_f32_32x32x16_f16(aH[0], bH[1], acc[0][1], 0, 0, 0); \
    acc[1][0] = __builtin_amdgcn_mfma_f32_32x32x16_f16(aH[1], bH[0], acc[1][0], 0, 0, 0); \
    acc[1][1] = __builtin_amdgcn_mfma_f32_32x32x16_f16(aH[1], bH[1], acc[1][1], 0, 0, 0); \
    acc[0][0] = __builtin_amdgcn_mfma_f32_32x32x16_f16(aH[0], bL[0], acc[0][0], 0, 0, 0); \
    acc[0][1] = __builtin_amdgcn_mfma_f32_32x32x16_f16(aH[0], bL[1], acc[0][1], 0, 0, 0); \
    acc[1][0] = __builtin_amdgcn_mfma_f32_32x32x16_f16(aH[1], bL[0], acc[1][0], 0, 0, 0); \
    acc[1][1] = __builtin_amdgcn_mfma_f32_32x32x16_f16(aH[1], bL[1], acc[1][1], 0, 0, 0); \
    acc[0][0] = __builtin_amdgcn_mfma_f32_32x32x16_f16(aL[0], bH[0], acc[0][0], 0, 0, 0); \
    acc[0][1] = __builtin_amdgcn_mfma_f32_32x32x16_f16(aL[0], bH[1], acc[0][1], 0, 0, 0); \
    acc[1][0] = __builtin_amdgcn_mfma_f32_32x32x16_f16(aL[1], bH[0], acc[1][0], 0, 0, 0); \
    acc[1][1] = __builtin_amdgcn_mfma_f32_32x32x16_f16(aL[1], bH[1], acc[1][1], 0, 0, 0); \
  }

  // prologue: A-set = k-step 0, B-set = k-step 1
  f32x4 wvA  = *(const f32x4*)(wsrc);
  f32x4 xv0A = *(const f32x4*)(xsrc);
  f32x4 xv1A = *(const f32x4*)(xsrc + 4);
  f32x4 wvB  = *(const f32x4*)(wsrc + 16);
  f32x4 xv0B = *(const f32x4*)(xsrc + 16);
  f32x4 xv1B = *(const f32x4*)(xsrc + 16 + 4);

  STAGE(0, wvA, xv0A, xv1A);     // k0 -> buf0
  __syncthreads();
  {                              // prefetch A <- k2
    wvA  = *(const f32x4*)(wsrc + 32);
    xv0A = *(const f32x4*)(xsrc + 32);
    xv1A = *(const f32x4*)(xsrc + 32 + 4);
  }

  for (int s = 0; s < NST; s += 2) {
    // phase 1: stage k_{s+1} -> buf1, compute k_s from buf0
    STAGE(1, wvB, xv0B, xv1B);
    COMPUTE(0);
    __syncthreads();
    if (s + 3 < NST) {           // prefetch B <- k_{s+3}
      const int ko = (s + 3) * 16;
      wvB  = *(const f32x4*)(wsrc + ko);
      xv0B = *(const f32x4*)(xsrc + ko);
      xv1B = *(const f32x4*)(xsrc + ko + 4);
    }
    // phase 2: stage k_{s+2} -> buf0, compute k_{s+1} from buf1
    if (s + 2 < NST) STAGE(0, wvA, xv0A, xv1A);
    COMPUTE(1);
    __syncthreads();
    if (s + 4 < NST) {           // prefetch A <- k_{s+4}
      const int ko = (s + 4) * 16;
      wvA  = *(const f32x4*)(wsrc + ko);
      xv0A = *(const f32x4*)(xsrc + ko);
      xv1A = *(const f32x4*)(xsrc + ko + 4);
    }
  }

  float* dst = atomic_mode ? outp : outp + (size_t)blockIdx.y * G4 * TS;
#pragma unroll
  for (int mi = 0; mi < 2; ++mi)
#pragma unroll
    for (int ni = 0; ni < 2; ++ni)
#pragma unroll
      for (int rg = 0; rg < 16; ++rg) {
        const int j = j0 + jw + mi * 32 + (rg & 3) + 8 * (rg >> 2) + 4 * kh;
        const int t = tw + ni * 32 + l31;
        if (atomic_mode) atomicAdd(&dst[(size_t)j * TS + t], acc[mi][ni][rg]);
        else             dst[(size_t)j * TS + t] = acc[mi][ni][rg];
      }
}

// ---------------------------------------------------------------------------
// Kernel 1b (xpart path): xprojT[j][t] = sum_ks xpartT[ks][j][t] + biases[j]
// (r8-proven form)
// ---------------------------------------------------------------------------
__global__ __launch_bounds__(256) void xproj_reduce(
    const float* __restrict__ xpartT, int nks,
    const float* __restrict__ b_ih, const float* __restrict__ b_hh,
    float* __restrict__ xprojT)
{
  const int idx = (blockIdx.x * 256 + threadIdx.x) * 4;
  float4 s = *(const float4*)(xpartT + idx);
  for (int ks = 1; ks < nks; ++ks) {
    float4 p = *(const float4*)(xpartT + (size_t)ks * G4 * TS + idx);
    s.x += p.x; s.y += p.y; s.z += p.z; s.w += p.w;
  }
  const int j = idx >> 8;  // TS = 256
  const float bias = b_ih[j] + b_hh[j];
  s.x += bias; s.y += bias; s.z += bias; s.w += bias;
  *(float4*)(xprojT + idx) = s;
}

// ---------------------------------------------------------------------------
// Kernel 1c (atomic path): xprojT[j][t] = b_ih[j] + b_hh[j]  (init target)
// ---------------------------------------------------------------------------
__global__ __launch_bounds__(256) void bias_init(
    const float* __restrict__ b_ih, const float* __restrict__ b_hh,
    float* __restrict__ xprojT)
{
  const int j = blockIdx.x;
  xprojT[(size_t)j * TS + threadIdx.x] = b_ih[j] + b_hh[j];
}

// ---------------------------------------------------------------------------
// Kernel 2: persistent LSTM scan — byte-identical to the r8-measured 638 µs
// kernel (r9's "safe" micro-opts regressed it 638->681; reverted).
// ---------------------------------------------------------------------------
#define NWG 128
#define UPW 8

__global__ __launch_bounds__(256, 1) void lstm_scan(
    const float* __restrict__ W_hh,    // (4096, 1024)
    const float* __restrict__ xprojT,  // (4096, 256)  j-major, biases included
    u64* __restrict__ hmsg)            // (2, 1024) packed {tag,val}
{
  const int tid = threadIdx.x;
  const int w = blockIdx.x;
  const int u0 = w * UPW;
  const int r = tid >> 3;            // 0..31 local row
  const int sub = tid & 7;           // 8 lanes per row, 128 elems each
  const int gate = r >> 3;           // 0..3
  const int uu = r & 7;              // 0..7
  const int hrow = gate * HID + u0 + uu;

  __shared__ __align__(16) float h_lds[8 * 132];
  __shared__ float gates_lds[32];
  __shared__ float c_lds[UPW];

  // my 128-float W_hh segment in registers
  float4 Wreg[32];
  const float4* wp = (const float4*)(W_hh + (size_t)hrow * HID + sub * 128);
#pragma unroll
  for (int i = 0; i < 32; ++i) Wreg[i] = wp[i];

  const float* xrow = xprojT + (size_t)hrow * TS;

  if (tid < UPW) c_lds[tid] = 0.f;
  __syncthreads();

  for (int t = 0; t < TS; ++t) {
    // prefetch my xproj element early (hides L1/L2 latency behind the spin)
    float xp = 0.f;
    if (sub == 0) xp = xrow[t];

    float partial = 0.f;
    if (t > 0) {
      const u64* slot = hmsg + (t & 1) * HID;
      const u32 tt = (u32)t;
      u64 m0, m1, m2, m3;
      // spin on slot 0 only (1 load/thread/iter — proven-safe poll rate)
      do {
        m0 = __hip_atomic_load(&slot[tid * 4 + 0], __ATOMIC_RELAXED,
                               __HIP_MEMORY_SCOPE_AGENT);
      } while ((u32)(m0 >> 32) != tt);
      // slots 1-3: batch issue (one round-trip), then verify
      m1 = __hip_atomic_load(&slot[tid * 4 + 1], __ATOMIC_RELAXED,
                             __HIP_MEMORY_SCOPE_AGENT);
      m2 = __hip_atomic_load(&slot[tid * 4 + 2], __ATOMIC_RELAXED,
                             __HIP_MEMORY_SCOPE_AGENT);
      m3 = __hip_atomic_load(&slot[tid * 4 + 3], __ATOMIC_RELAXED,
                             __HIP_MEMORY_SCOPE_AGENT);
      while ((u32)(m1 >> 32) != tt)
        m1 = __hip_atomic_load(&slot[tid * 4 + 1], __ATOMIC_RELAXED,
                               __HIP_MEMORY_SCOPE_AGENT);
      while ((u32)(m2 >> 32) != tt)
        m2 = __hip_atomic_load(&slot[tid * 4 + 2], __ATOMIC_RELAXED,
                               __HIP_MEMORY_SCOPE_AGENT);
      while ((u32)(m3 >> 32) != tt)
        m3 = __hip_atomic_load(&slot[tid * 4 + 3], __ATOMIC_RELAXED,
                               __HIP_MEMORY_SCOPE_AGENT);
      __syncthreads();  // B1: prev step's h_lds readers done
      const int st = tid >> 5;
      const int off = (tid & 31) * 4;
      h_lds[st * 132 + off + 0] = __uint_as_float((u32)m0);
      h_lds[st * 132 + off + 1] = __uint_as_float((u32)m1);
      h_lds[st * 132 + off + 2] = __uint_as_float((u32)m2);
      h_lds[st * 132 + off + 3] = __uint_as_float((u32)m3);
      __syncthreads();  // B2: h_lds ready
      const float4* hl = (const float4*)(h_lds + sub * 132);
#pragma unroll
      for (int i = 0; i < 32; ++i) {
        float4 h4 = hl[i];
        partial += Wreg[i].x * h4.x + Wreg[i].y * h4.y +
                   Wreg[i].z * h4.z + Wreg[i].w * h4.w;
      }
    }
    // reduce across the 8 sub-lanes of this row (same wave)
    partial += __shfl_xor(partial, 1, 64);
    partial += __shfl_xor(partial, 2, 64);
    partial += __shfl_xor(partial, 4, 64);
    if (sub == 0) {
      float gsum = partial + xp;
      float act = (gate == 2) ? tanhf(gsum) : 1.f / (1.f + expf(-gsum));
      gates_lds[gate * 8 + uu] = act;
    }
    __syncthreads();  // B3: gates ready
    if (tid < UPW) {
      float iv = gates_lds[0 * 8 + tid];
      float fv = gates_lds[1 * 8 + tid];
      float gv = gates_lds[2 * 8 + tid];
      float ov = gates_lds[3 * 8 + tid];
      float c = fv * c_lds[tid] + iv * gv;
      c_lds[tid] = c;
      float hnew = ov * tanhf(c);
      u64 msg = ((u64)(u32)(t + 1) << 32) | (u64)__float_as_uint(hnew);
      __hip_atomic_store(&hmsg[((t + 1) & 1) * HID + u0 + tid], msg,
                         __ATOMIC_RELAXED, __HIP_MEMORY_SCOPE_AGENT);
    }
    // no trailing barrier needed: B1/B3 of the next iteration protect LDS
  }
}

// ---------------------------------------------------------------------------
// Kernel 3: out[j] = dot(fc_w[j,:], h_T) + fc_b[j].
// ---------------------------------------------------------------------------
__global__ __launch_bounds__(256) void fc_kernel(
    const float* __restrict__ fc_w,  // (12288, 1024)
    const float* __restrict__ fc_b,  // (12288)
    const u64* __restrict__ hmsg,    // h_T packed at slot 0
    float* __restrict__ out)         // (12288)
{
  __shared__ float h_s[HID];
  const int tid = threadIdx.x;
  for (int k = tid; k < HID; k += 256)
    h_s[k] = __uint_as_float((u32)hmsg[k]);
  __syncthreads();
  const int r = tid >> 2;    // 0..63
  const int sub = tid & 3;   // 256 elems each
  const int j = blockIdx.x * 64 + r;
  const float4* wrow = (const float4*)(fc_w + (size_t)j * HID + sub * 256);
  const float4* hp = (const float4*)(h_s + sub * 256);
  float s = 0.f;
#pragma unroll
  for (int i = 0; i < 64; ++i) {
    float4 wv = wrow[i];
    float4 hv = hp[i];
    s += wv.x * hv.x + wv.y * hv.y + wv.z * hv.z + wv.w * hv.w;
  }
  s += __shfl_xor(s, 1, 64);
  s += __shfl_xor(s, 2, 64);
  if (sub == 0) out[j] = s + fc_b[j];
}

// ---------------------------------------------------------------------------
extern "C" void kernel_launch(void* const* d_in, const int* in_sizes, int n_in,
                              void* d_out, int out_size, void* d_ws, size_t ws_size,
                              hipStream_t stream) {
  const float* frames = (const float*)d_in[0];  // (256,3,64,64)
  const float* W_ih   = (const float*)d_in[1];  // (4096,12288)
  const float* W_hh   = (const float*)d_in[2];  // (4096,1024)
  const float* b_ih   = (const float*)d_in[3];  // (4096)
  const float* b_hh   = (const float*)d_in[4];  // (4096)
  const float* fc_w   = (const float*)d_in[5];  // (12288,1024)
  const float* fc_b   = (const float*)d_in[6];  // (12288)
  float* out = (float*)d_out;

  const size_t XB = (size_t)TS * G4 * 4;  // 4 MB
  char* ws = (char*)d_ws;
  float* xprojT = (float*)ws;             // 4 MB, j-major, biases included
  const bool xpart_path = ws_size >= XB * (1 + NKS) + (1 << 20);

  if (xpart_path) {
    float* xpartT = (float*)(ws + XB);                 // 8 x 4 MB
    u64*   hmsg   = (u64*)(ws + XB * (1 + NKS));       // 16 KB
    xproj_gemm<<<dim3(G4 / 128, NKS), 512, 0, stream>>>(frames, W_ih, xpartT, 0);
    xproj_reduce<<<dim3(G4 * TS / 4 / 256), 256, 0, stream>>>(xpartT, NKS, b_ih, b_hh, xprojT);
    lstm_scan<<<dim3(NWG), 256, 0, stream>>>(W_hh, xprojT, hmsg);
    fc_kernel<<<dim3(12288 / 64), 256, 0, stream>>>(fc_w, fc_b, hmsg, out);
  } else {
    u64* hmsg = (u64*)(ws + XB);
    bias_init<<<dim3(G4), 256, 0, stream>>>(b_ih, b_hh, xprojT);
    xproj_gemm<<<dim3(G4 / 128, NKS), 512, 0, stream>>>(frames, W_ih, xprojT, 1);
    lstm_scan<<<dim3(NWG), 256, 0, stream>>>(W_hh, xprojT, hmsg);
    fc_kernel<<<dim3(12288 / 64), 256, 0, stream>>>(fc_w, fc_b, hmsg, out);
  }
  // hmsg deliberately NOT initialized: stale tags (255/256/0xAA) never match
  // the expected tags [1,256] at their parity slots.
}